// Round 14
// baseline (262.358 us; speedup 1.0000x reference)
//
#include <hip/hip_runtime.h>

#define NN 50000
#define EE 150000
#define BN_EPS 1e-5f
#define SLOPE 0.01f
#define SCAN_B 196          // ceil((NN+1)/256)
#define AGG_B  782          // ceil(NN/64)
#define CAP    256          // staged message rows per block chunk (avg span 192)

typedef __attribute__((ext_vector_type(8))) short bf16x8;
typedef __attribute__((ext_vector_type(4))) float f32x4;

// ---------------- CSR build ----------------
__global__ __launch_bounds__(256) void k_count(const int* __restrict__ ei, int* __restrict__ cnt) {
    int e = blockIdx.x * blockDim.x + threadIdx.x;
    if (e < EE) atomicAdd(&cnt[ei[EE + e]], 1);
}

__global__ __launch_bounds__(256) void k_scanA(const int* __restrict__ cnt,
                                               int* __restrict__ rowptr,
                                               int* __restrict__ bsum) {
    __shared__ int buf[256];
    int t = threadIdx.x;
    int idx = blockIdx.x * 256 + t;
    int v = (idx <= NN) ? cnt[idx] : 0;
    buf[t] = v;
    __syncthreads();
    for (int off = 1; off < 256; off <<= 1) {
        int add = (t >= off) ? buf[t - off] : 0;
        __syncthreads();
        buf[t] += add;
        __syncthreads();
    }
    if (idx <= NN) rowptr[idx] = buf[t] - v;
    if (t == 255) bsum[blockIdx.x] = buf[255];
}

__global__ __launch_bounds__(256) void k_scanB(int* __restrict__ bsum) {
    __shared__ int buf[256];
    int t = threadIdx.x;
    int v = (t < SCAN_B) ? bsum[t] : 0;
    buf[t] = v;
    __syncthreads();
    for (int off = 1; off < 256; off <<= 1) {
        int add = (t >= off) ? buf[t - off] : 0;
        __syncthreads();
        buf[t] += add;
        __syncthreads();
    }
    if (t < SCAN_B) bsum[t] = buf[t] - v;
}

__global__ __launch_bounds__(256) void k_scanC(int* __restrict__ rowptr,
                                               int* __restrict__ cursor,
                                               const int* __restrict__ bsum) {
    int idx = blockIdx.x * 256 + threadIdx.x;
    if (idx <= NN) {
        int r = rowptr[idx] + bsum[blockIdx.x];
        rowptr[idx] = r;
        cursor[idx] = r;
    }
}

// materialize permuted edge data: srcp[slot] = src node, eap[slot] = edge_attr
__global__ __launch_bounds__(256) void k_fill(const int* __restrict__ ei,
                                              const float* __restrict__ ea,
                                              int* __restrict__ cursor,
                                              int* __restrict__ srcp,
                                              float2* __restrict__ eap) {
    int e = blockIdx.x * blockDim.x + threadIdx.x;
    if (e < EE) {
        int pos = atomicAdd(&cursor[ei[EE + e]], 1);
        srcp[pos] = ei[e];
        eap[pos] = ((const float2*)ea)[e];
    }
}

// pre-swizzle Wf = [W2 k=0..9 ; b2] into bf16 A-fragment order
__global__ __launch_bounds__(256) void k_wprep(const float* __restrict__ netW2,
                                               const float* __restrict__ netb2,
                                               unsigned* __restrict__ Wfz) {
    int layer = blockIdx.y;
    int idx = blockIdx.x * 256 + threadIdx.x;      // < 5632
    if (idx >= 5632) return;
    const float* W2 = netW2 + layer * 10240;
    const float* b2 = netb2 + layer * 1024;
    int frag = idx >> 8;
    int rem  = idx & 255;
    int lane = rem >> 2;
    int j0   = (rem & 3) * 2;
    int tile = frag & 1;
    int kstep = frag >> 1;
    int o  = tile * 16 + (lane & 15);
    int kk = kstep * 32 + (lane >> 4) * 8 + j0;
    float v0, v1;
    if (kk < 320) {
        int base = (kk >> 5) * 1024 + (kk & 31) * 32 + o;
        v0 = W2[base];
        v1 = W2[base + 32];
    } else {
        int base = (kk - 320) * 32 + o;
        v0 = b2[base];
        v1 = b2[base + 32];
    }
    Wfz[layer * 5632 + idx] =
        __builtin_amdgcn_perm(__float_as_uint(v1), __float_as_uint(v0), 0x07060302u);
}

// in-block BN finalize: stats -> scale/shift in LDS (caller syncs)
__device__ __forceinline__ void bn_scsh(const float* __restrict__ stats,
                                        const float* __restrict__ gamma,
                                        const float* __restrict__ beta,
                                        int flag, float* sc, float* sh) {
    if (flag && threadIdx.x < 32) {
        int o = threadIdx.x;
        float mu = stats[o] * (1.0f / NN);
        float var = stats[32 + o] * (1.0f / NN) - mu * mu;
        float s = gamma[o] * rsqrtf(var + BN_EPS);
        sc[o] = s;
        sh[o] = fmaf(-mu, s, beta[o]);
    }
}

// ---------------- fused per-layer kernel ----------------
// Block = 64 nodes + contiguous CSR slot span (~192 edges). Pipeline: issue all
// gather loads (2 passes) -> phase-1 root GEMM hides latency -> MFMA passes ->
// sync -> per-node LDS sum. srcp/eap are slot-ordered (coalesced, 1-level chain).
__global__ __launch_bounds__(512) void k_layer(
    const float* __restrict__ h, const int* __restrict__ srcp,
    const float2* __restrict__ eap, const float* __restrict__ W1,
    const float* __restrict__ b1, const unsigned* __restrict__ Wfz,
    const int* __restrict__ rowptr,
    const float* __restrict__ root, const float* __restrict__ bias,
    const float* __restrict__ stats_prev, const float* __restrict__ gamma,
    const float* __restrict__ beta, int flag,
    float* __restrict__ hpre, float* __restrict__ stats_out)
{
    __shared__ float smb[CAP * 36];      // 36.9 KB staged message rows (36-float pad)
    __shared__ float sc[32], sh[32];
    __shared__ float ls[2][8][8][4];

    int t = threadIdx.x;
    bn_scsh(stats_prev, gamma, beta, flag, sc, sh);
    __syncthreads();

    int v0 = blockIdx.x * 64;
    int vend = v0 + 64 < NN ? v0 + 64 : NN;
    int p_start = rowptr[v0];
    int span = rowptr[vend] - p_start;

    int v = v0 + (t >> 3);
    int cg = t & 7;
    bool nv = v < NN;
    int r0 = nv ? rowptr[v] - p_start : 0;
    int r1 = nv ? rowptr[v + 1] - p_start : 0;

    // phase-1 node row: issue loads early
    float hn[32];
    {
        const float4* hp = (const float4*)(h + (nv ? v : v0) * 32);
#pragma unroll
        for (int q = 0; q < 8; ++q) {
            float4 tt = hp[q];
            hn[4 * q] = tt.x; hn[4 * q + 1] = tt.y; hn[4 * q + 2] = tt.z; hn[4 * q + 3] = tt.w;
        }
    }

    float4 acc = make_float4(0.f, 0.f, 0.f, 0.f);
    int lane = t & 63;
    int w = t >> 6;
    int col = lane & 15;
    int chunk = lane >> 4;               // B-frag k-chunk (h channels chunk*8..+7)
    int i0 = chunk * 8;

    bool did1 = false;
    for (int c0 = 0; c0 < span; c0 += CAP) {
        int csize = span - c0 < CAP ? span - c0 : CAP;

        // ---- issue gather loads for both passes (max MLP) ----
        int slA = w * 16 + col;
        int slB = slA + 128;
        bool evA = slA < csize;
        bool evB = slB < csize;
        int sA = evA ? srcp[p_start + c0 + slA] : 0;
        int sB = evB ? srcp[p_start + c0 + slB] : 0;
        float2 aA = evA ? eap[p_start + c0 + slA] : make_float2(0.f, 0.f);
        float2 aB = evB ? eap[p_start + c0 + slB] : make_float2(0.f, 0.f);
        float hvA[8], hvB[8];
        *(float4*)&hvA[0] = *(const float4*)(h + sA * 32 + i0);
        *(float4*)&hvA[4] = *(const float4*)(h + sA * 32 + i0 + 4);
        *(float4*)&hvB[0] = *(const float4*)(h + sB * 32 + i0);
        *(float4*)&hvB[4] = *(const float4*)(h + sB * 32 + i0 + 4);

        // ---- phase 1 under the gather latency: bias + norm(h[v]) @ root ----
        if (!did1) {
            did1 = true;
            if (nv) {
                if (flag) {
#pragma unroll
                    for (int i = 0; i < 32; ++i) {
                        float y = fmaf(hn[i], sc[i], sh[i]);
                        hn[i] = y > 0.f ? y : SLOPE * y;
                    }
                }
                acc = ((const float4*)bias)[cg];
#pragma unroll
                for (int i = 0; i < 32; ++i) {
                    float4 r = ((const float4*)(root + i * 32))[cg];
                    acc.x = fmaf(hn[i], r.x, acc.x);
                    acc.y = fmaf(hn[i], r.y, acc.y);
                    acc.z = fmaf(hn[i], r.z, acc.z);
                    acc.w = fmaf(hn[i], r.w, acc.w);
                }
            }
        }

        // ---- pass A ----
        {
            if (flag) {
#pragma unroll
                for (int j = 0; j < 8; ++j) {
                    float y = fmaf(hvA[j], sc[i0 + j], sh[i0 + j]);
                    hvA[j] = y > 0.f ? y : SLOPE * y;
                }
            }
            float ekv[11];
#pragma unroll
            for (int k = 0; k < 10; ++k)
                ekv[k] = fmaxf(fmaf(aA.x, W1[k], fmaf(aA.y, W1[10 + k], b1[k])), 0.0f);
            ekv[10] = 1.0f;
            f32x4 m0 = {0.f, 0.f, 0.f, 0.f};
            f32x4 m1 = {0.f, 0.f, 0.f, 0.f};
#pragma unroll
            for (int k = 0; k < 11; ++k) {
                float ekk = ekv[k];
                union { unsigned u[4]; bf16x8 v; } B;
                B.u[0] = __builtin_amdgcn_perm(__float_as_uint(ekk * hvA[1]), __float_as_uint(ekk * hvA[0]), 0x07060302u);
                B.u[1] = __builtin_amdgcn_perm(__float_as_uint(ekk * hvA[3]), __float_as_uint(ekk * hvA[2]), 0x07060302u);
                B.u[2] = __builtin_amdgcn_perm(__float_as_uint(ekk * hvA[5]), __float_as_uint(ekk * hvA[4]), 0x07060302u);
                B.u[3] = __builtin_amdgcn_perm(__float_as_uint(ekk * hvA[7]), __float_as_uint(ekk * hvA[6]), 0x07060302u);
                bf16x8 A0 = *(const bf16x8*)(Wfz + (k * 2)     * 256 + lane * 4);
                bf16x8 A1 = *(const bf16x8*)(Wfz + (k * 2 + 1) * 256 + lane * 4);
                m0 = __builtin_amdgcn_mfma_f32_16x16x32_bf16(A0, B.v, m0, 0, 0, 0);
                m1 = __builtin_amdgcn_mfma_f32_16x16x32_bf16(A1, B.v, m1, 0, 0, 0);
            }
            if (evA) {
                *(f32x4*)&smb[slA * 36 + chunk * 4]      = m0;
                *(f32x4*)&smb[slA * 36 + 16 + chunk * 4] = m1;
            }
        }

        // ---- pass B (uniform skip when chunk fits one pass) ----
        if (csize > 128) {
            if (flag) {
#pragma unroll
                for (int j = 0; j < 8; ++j) {
                    float y = fmaf(hvB[j], sc[i0 + j], sh[i0 + j]);
                    hvB[j] = y > 0.f ? y : SLOPE * y;
                }
            }
            float ekv[11];
#pragma unroll
            for (int k = 0; k < 10; ++k)
                ekv[k] = fmaxf(fmaf(aB.x, W1[k], fmaf(aB.y, W1[10 + k], b1[k])), 0.0f);
            ekv[10] = 1.0f;
            f32x4 m0 = {0.f, 0.f, 0.f, 0.f};
            f32x4 m1 = {0.f, 0.f, 0.f, 0.f};
#pragma unroll
            for (int k = 0; k < 11; ++k) {
                float ekk = ekv[k];
                union { unsigned u[4]; bf16x8 v; } B;
                B.u[0] = __builtin_amdgcn_perm(__float_as_uint(ekk * hvB[1]), __float_as_uint(ekk * hvB[0]), 0x07060302u);
                B.u[1] = __builtin_amdgcn_perm(__float_as_uint(ekk * hvB[3]), __float_as_uint(ekk * hvB[2]), 0x07060302u);
                B.u[2] = __builtin_amdgcn_perm(__float_as_uint(ekk * hvB[5]), __float_as_uint(ekk * hvB[4]), 0x07060302u);
                B.u[3] = __builtin_amdgcn_perm(__float_as_uint(ekk * hvB[7]), __float_as_uint(ekk * hvB[6]), 0x07060302u);
                bf16x8 A0 = *(const bf16x8*)(Wfz + (k * 2)     * 256 + lane * 4);
                bf16x8 A1 = *(const bf16x8*)(Wfz + (k * 2 + 1) * 256 + lane * 4);
                m0 = __builtin_amdgcn_mfma_f32_16x16x32_bf16(A0, B.v, m0, 0, 0, 0);
                m1 = __builtin_amdgcn_mfma_f32_16x16x32_bf16(A1, B.v, m1, 0, 0, 0);
            }
            if (evB) {
                *(f32x4*)&smb[slB * 36 + chunk * 4]      = m0;
                *(f32x4*)&smb[slB * 36 + 16 + chunk * 4] = m1;
            }
        }
        __syncthreads();

        // ---- per-node sum from LDS ----
        if (nv) {
            int q0 = r0 - c0; q0 = q0 > 0 ? q0 : 0;
            int q1 = r1 - c0; q1 = q1 < csize ? q1 : csize;
            for (int p = q0; p < q1; ++p) {
                float4 tt = *(const float4*)&smb[p * 36 + cg * 4];
                acc.x += tt.x; acc.y += tt.y; acc.z += tt.z; acc.w += tt.w;
            }
        }
        __syncthreads();
    }

    // span==0 corner: phase 1 never ran in-loop
    if (!did1 && nv) {
        if (flag) {
#pragma unroll
            for (int i = 0; i < 32; ++i) {
                float y = fmaf(hn[i], sc[i], sh[i]);
                hn[i] = y > 0.f ? y : SLOPE * y;
            }
        }
        acc = ((const float4*)bias)[cg];
#pragma unroll
        for (int i = 0; i < 32; ++i) {
            float4 r = ((const float4*)(root + i * 32))[cg];
            acc.x = fmaf(hn[i], r.x, acc.x);
            acc.y = fmaf(hn[i], r.y, acc.y);
            acc.z = fmaf(hn[i], r.z, acc.z);
            acc.w = fmaf(hn[i], r.w, acc.w);
        }
    }

    if (nv) ((float4*)(hpre + v * 32))[cg] = acc;

    // ---- BN stats tail ----
    float ss[8] = { acc.x, acc.y, acc.z, acc.w,
                    acc.x * acc.x, acc.y * acc.y, acc.z * acc.z, acc.w * acc.w };
#pragma unroll
    for (int d = 8; d < 64; d <<= 1) {
#pragma unroll
        for (int j = 0; j < 8; ++j) ss[j] += __shfl_xor(ss[j], d);
    }
    int wave = t >> 6, lane2 = t & 63;
    if (lane2 < 8) {
#pragma unroll
        for (int j = 0; j < 4; ++j) {
            ls[0][wave][lane2][j] = ss[j];
            ls[1][wave][lane2][j] = ss[4 + j];
        }
    }
    __syncthreads();
    if (t < 64) {
        int stat = t >> 5, idx = t & 31;
        int cgg = idx >> 2, ch = idx & 3;
        float val = 0.f;
#pragma unroll
        for (int wv = 0; wv < 8; ++wv) val += ls[stat][wv][cgg][ch];
        unsafeAtomicAdd(&stats_out[stat * 32 + idx], val);
    }
}

// final-layer norm fused
__global__ __launch_bounds__(256) void k_logits(const float* __restrict__ h,
                                                const float* __restrict__ fcW,
                                                const float* __restrict__ fcb,
                                                const float* __restrict__ stats,
                                                const float* __restrict__ gamma,
                                                const float* __restrict__ beta,
                                                float* __restrict__ out) {
    __shared__ float sc[32], sh[32];
    bn_scsh(stats, gamma, beta, 1, sc, sh);
    __syncthreads();

    int v = blockIdx.x * blockDim.x + threadIdx.x;
    if (v >= NN) return;
    float hv[32];
    const float4* hp = (const float4*)(h + v * 32);
#pragma unroll
    for (int q = 0; q < 8; ++q) {
        float4 t = hp[q];
        hv[4 * q] = t.x; hv[4 * q + 1] = t.y; hv[4 * q + 2] = t.z; hv[4 * q + 3] = t.w;
    }
#pragma unroll
    for (int i = 0; i < 32; ++i) {
        float y = fmaf(hv[i], sc[i], sh[i]);
        hv[i] = y > 0.f ? y : SLOPE * y;
    }
    float lg[13];
#pragma unroll
    for (int c = 0; c < 13; ++c) lg[c] = fcb[c];
#pragma unroll
    for (int i = 0; i < 32; ++i) {
        float z = hv[i];
#pragma unroll
        for (int c = 0; c < 13; ++c) lg[c] = fmaf(z, fcW[i * 13 + c], lg[c]);
    }
    float mx = lg[0];
#pragma unroll
    for (int c = 1; c < 13; ++c) mx = fmaxf(mx, lg[c]);
    float sum = 0.0f;
#pragma unroll
    for (int c = 0; c < 13; ++c) sum += expf(lg[c] - mx);
    float lse = mx + logf(sum);
#pragma unroll
    for (int c = 0; c < 13; ++c) out[v * 13 + c] = lg[c] - lse;
}

// ---------------- launch ----------------
extern "C" void kernel_launch(void* const* d_in, const int* in_sizes, int n_in,
                              void* d_out, int out_size, void* d_ws, size_t ws_size,
                              hipStream_t stream) {
    const float* x     = (const float*)d_in[0];
    const int*   ei    = (const int*)  d_in[1];
    const float* ea    = (const float*)d_in[2];
    const float* netW1 = (const float*)d_in[3];
    const float* netb1 = (const float*)d_in[4];
    const float* netW2 = (const float*)d_in[5];
    const float* netb2 = (const float*)d_in[6];
    const float* root  = (const float*)d_in[7];
    const float* cbias = (const float*)d_in[8];
    const float* gamma = (const float*)d_in[9];
    const float* beta  = (const float*)d_in[10];
    const float* fcW   = (const float*)d_in[11];
    const float* fcb   = (const float*)d_in[12];
    float* out = (float*)d_out;

    char* w = (char*)d_ws;
    float*    hA     = (float*)   (w);                 //  6,400,000 B
    float*    hB     = (float*)   (w +  6400000);      //  6,400,000 B
    int*      rowptr = (int*)     (w + 12800000);      //    200,064 B
    int*      cursor = (int*)     (w + 13000064);      //    200,064 B
    int*      srcp   = (int*)     (w + 13200128);      //    600,000 B
    float2*   eap    = (float2*)  (w + 13800128);      //  1,200,000 B
    float*    stats  = (float*)   (w + 15000128);      //        768 B
    int*      bsum   = (int*)     (w + 15000896);      //      1,024 B
    unsigned* Wfz    = (unsigned*)(w + 15001920);      //     67,584 B
    int*      cnt    = (int*)     (w + 15069504);      //    200,064 B

    hipMemsetAsync(cnt, 0, (NN + 1) * sizeof(int), stream);
    hipMemsetAsync(stats, 0, 768, stream);

    k_wprep<<<dim3(22, 3), 256, 0, stream>>>(netW2, netb2, Wfz);
    k_count<<<(EE + 255) / 256, 256, 0, stream>>>(ei, cnt);
    k_scanA<<<SCAN_B, 256, 0, stream>>>(cnt, rowptr, bsum);
    k_scanB<<<1, 256, 0, stream>>>(bsum);
    k_scanC<<<SCAN_B, 256, 0, stream>>>(rowptr, cursor, bsum);
    k_fill <<<(EE + 255) / 256, 256, 0, stream>>>(ei, ea, cursor, srcp, eap);

    const float* hcur = x;
    float* bufs[2] = { hA, hB };
    for (int i = 0; i < 3; ++i) {
        float* hnext = bufs[i & 1];
        const float* stprev = stats + (i - 1) * 64;   // unused when i==0
        k_layer<<<AGG_B, 512, 0, stream>>>(
            hcur, srcp, eap, netW1 + i * 20, netb1 + i * 10, Wfz + i * 5632,
            rowptr, root + i * 1024, cbias + i * 32,
            stprev, gamma + (i - 1) * 32, beta + (i - 1) * 32, i > 0,
            hnext, stats + i * 64);
        hcur = hnext;
    }
    k_logits<<<(NN + 255) / 256, 256, 0, stream>>>(
        hcur, fcW, fcb, stats + 2 * 64, gamma + 2 * 32, beta + 2 * 32, out);
}